// Round 3
// baseline (437.844 us; speedup 1.0000x reference)
//
#include <hip/hip_runtime.h>

#define D 16
#define NBINS 256
#define CHUNKS 256
#define BLOCKS_PER_BIN 8

typedef __bf16 bf16x8 __attribute__((ext_vector_type(8)));
typedef float f32x4 __attribute__((ext_vector_type(4)));

// ---------- counting sort of edges by widx (256 bins, one pass) ----------

// Per-chunk histogram into transposed layout histT[w*CHUNKS + c].
__global__ __launch_bounds__(256) void hist_widx_kernel(const int* __restrict__ widx,
                                                        int* __restrict__ histT,
                                                        int E, int chunk) {
    __shared__ int h[NBINS];
    int c = blockIdx.x, t = threadIdx.x;
    h[t] = 0;
    __syncthreads();
    int s = c * chunk, e = min(E, s + chunk);
    for (int j = s + t; j < e; j += 256) atomicAdd(&h[widx[j]], 1);
    __syncthreads();
    histT[t * CHUNKS + c] = h[t];
}

// Per-block (1024-elem) exclusive scan, block totals to bsum.
__global__ __launch_bounds__(256) void scan1_kernel(int* __restrict__ a,
                                                    int* __restrict__ bsum, int n) {
    __shared__ int wsum[4];
    int t = threadIdx.x;
    int base = blockIdx.x * 1024 + t * 4;
    int c0 = (base + 0 < n) ? a[base + 0] : 0;
    int c1 = (base + 1 < n) ? a[base + 1] : 0;
    int c2 = (base + 2 < n) ? a[base + 2] : 0;
    int c3 = (base + 3 < n) ? a[base + 3] : 0;
    int tsum = c0 + c1 + c2 + c3;
    int lane = t & 63, wid = t >> 6;
    int incl = tsum;
    for (int d = 1; d < 64; d <<= 1) {
        int m = __shfl_up(incl, d, 64);
        if (lane >= d) incl += m;
    }
    if (lane == 63) wsum[wid] = incl;
    __syncthreads();
    if (t == 0) {
        int s = 0;
        for (int k = 0; k < 4; k++) { int tmp = wsum[k]; wsum[k] = s; s += tmp; }
        bsum[blockIdx.x] = s;
    }
    __syncthreads();
    int excl = incl - tsum + wsum[wid];
    if (base + 0 < n) a[base + 0] = excl;
    if (base + 1 < n) a[base + 1] = excl + c0;
    if (base + 2 < n) a[base + 2] = excl + c0 + c1;
    if (base + 3 < n) a[base + 3] = excl + c0 + c1 + c2;
}

__global__ void scan2_kernel(int* __restrict__ bsum, int nb) {
    if (threadIdx.x == 0 && blockIdx.x == 0) {
        int s = 0;
        for (int b = 0; b < nb; b++) { int t = bsum[b]; bsum[b] = s; s += t; }
    }
}

// Add block offsets; extract bucket starts bstart[w] = histT[w*CHUNKS + 0].
__global__ __launch_bounds__(256) void scan3_kernel(int* __restrict__ a,
                                                    const int* __restrict__ bsum,
                                                    int* __restrict__ bstart,
                                                    int n, int E) {
    int idx = blockIdx.x * 256 + threadIdx.x;
    if (idx < n) {
        int val = a[idx] + bsum[idx >> 10];
        a[idx] = val;
        if ((idx & (CHUNKS - 1)) == 0) bstart[idx / CHUNKS] = val;
    }
    if (idx == 0) bstart[NBINS] = E;
}

// Scatter (u,v) payloads into widx-sorted order.
__global__ __launch_bounds__(256) void scatter_widx_kernel(const int* __restrict__ u,
                                                           const int* __restrict__ v,
                                                           const int* __restrict__ widx,
                                                           const int* __restrict__ histT,
                                                           int2* __restrict__ sorted,
                                                           int E, int chunk) {
    __shared__ int loff[NBINS];
    int c = blockIdx.x, t = threadIdx.x;
    loff[t] = histT[t * CHUNKS + c];
    __syncthreads();
    int s = c * chunk, e = min(E, s + chunk);
    for (int j = s + t; j < e; j += 256) {
        int w = widx[j];
        int pos = atomicAdd(&loff[w], 1);
        sorted[pos] = make_int2(u[j], v[j]);
    }
}

// ---------- compute: one W per block (LDS), MFMA over 16 edges/wave-iter ----

__global__ __launch_bounds__(256) void mfma_compute_kernel(const float* __restrict__ x,
                                                           const float* __restrict__ W,
                                                           const int* __restrict__ bstart,
                                                           const int2* __restrict__ sorted,
                                                           float* __restrict__ out) {
    __shared__ float lw[256];
    int w = blockIdx.x / BLOCKS_PER_BIN;
    int sub = blockIdx.x % BLOCKS_PER_BIN;
    int t = threadIdx.x;
    lw[t] = W[w * 256 + t];
    __syncthreads();

    int bs = bstart[w], be = bstart[w + 1];
    int cnt = be - bs;
    int per = (cnt + BLOCKS_PER_BIN - 1) / BLOCKS_PER_BIN;
    int s = bs + sub * per;
    int e = min(be, s + per);
    if (s >= e) return;

    int lane = t & 63;
    int wave = t >> 6;
    int quad = lane >> 4;
    int m = lane & 15;

    // A = W[w], A[m][k]: k = quad*8 + j for quad<2 (K padded 16->32 with zeros).
    bf16x8 afrag;
    if (quad < 2) {
        #pragma unroll
        for (int j = 0; j < 8; j++) afrag[j] = (__bf16)lw[m * 16 + quad * 8 + j];
    } else {
        #pragma unroll
        for (int j = 0; j < 8; j++) afrag[j] = (__bf16)0.0f;
    }

    for (int base = s + wave * 16; base < e; base += 64) {
        int j = base + m;            // edge index for column m
        bool valid = j < e;
        int2 uv = valid ? sorted[j] : make_int2(0, 0);

        // B[k][n]: n = m (edge), k = quad*8 + jj -> x[u_n][quad*8 .. quad*8+7]
        bf16x8 bfrag;
        if (quad < 2 && valid) {
            const float* xp = x + (size_t)uv.x * D + quad * 8;
            float4 xa = *(const float4*)xp;
            float4 xb = *(const float4*)(xp + 4);
            bfrag[0] = (__bf16)xa.x; bfrag[1] = (__bf16)xa.y;
            bfrag[2] = (__bf16)xa.z; bfrag[3] = (__bf16)xa.w;
            bfrag[4] = (__bf16)xb.x; bfrag[5] = (__bf16)xb.y;
            bfrag[6] = (__bf16)xb.z; bfrag[7] = (__bf16)xb.w;
        } else {
            #pragma unroll
            for (int k = 0; k < 8; k++) bfrag[k] = (__bf16)0.0f;
        }

        f32x4 acc = {0.f, 0.f, 0.f, 0.f};
        acc = __builtin_amdgcn_mfma_f32_16x16x32_bf16(afrag, bfrag, acc, 0, 0, 0);

        // D: col = m (edge), row = quad*4 + r  -> out[v*16 + row]
        if (valid) {
            float* op = out + (size_t)uv.y * D + quad * 4;
            atomicAdd(op + 0, acc[0]);
            atomicAdd(op + 1, acc[1]);
            atomicAdd(op + 2, acc[2]);
            atomicAdd(op + 3, acc[3]);
        }
    }
}

__global__ __launch_bounds__(256) void relu_kernel(float* __restrict__ out, int n4) {
    int i = blockIdx.x * 256 + threadIdx.x;
    if (i >= n4) return;
    float4* p = (float4*)out + i;
    float4 val = *p;
    val.x = fmaxf(val.x, 0.0f); val.y = fmaxf(val.y, 0.0f);
    val.z = fmaxf(val.z, 0.0f); val.w = fmaxf(val.w, 0.0f);
    *p = val;
}

// ---------------- fallback (round-1 path) if workspace too small ----------

__global__ __launch_bounds__(256) void edge_scatter_kernel(
    const float* __restrict__ x, const float* __restrict__ W,
    const int* __restrict__ u, const int* __restrict__ v,
    const int* __restrict__ widx, float* __restrict__ out, int E) {
    int tid = blockIdx.x * 256 + threadIdx.x;
    int e = tid >> 4;
    int o = tid & 15;
    if (e >= E) return;
    int w = widx[e], uu = u[e], vv = v[e];
    const float* Wr = W + (size_t)w * (D * D) + o * D;
    float4 w0 = *(const float4*)(Wr + 0);
    float4 w1 = *(const float4*)(Wr + 4);
    float4 w2 = *(const float4*)(Wr + 8);
    float4 w3 = *(const float4*)(Wr + 12);
    float xv = x[uu * D + o];
    float acc = 0.0f;
    acc += w0.x * __shfl(xv, 0, 16);  acc += w0.y * __shfl(xv, 1, 16);
    acc += w0.z * __shfl(xv, 2, 16);  acc += w0.w * __shfl(xv, 3, 16);
    acc += w1.x * __shfl(xv, 4, 16);  acc += w1.y * __shfl(xv, 5, 16);
    acc += w1.z * __shfl(xv, 6, 16);  acc += w1.w * __shfl(xv, 7, 16);
    acc += w2.x * __shfl(xv, 8, 16);  acc += w2.y * __shfl(xv, 9, 16);
    acc += w2.z * __shfl(xv, 10, 16); acc += w2.w * __shfl(xv, 11, 16);
    acc += w3.x * __shfl(xv, 12, 16); acc += w3.y * __shfl(xv, 13, 16);
    acc += w3.z * __shfl(xv, 14, 16); acc += w3.w * __shfl(xv, 15, 16);
    atomicAdd(out + (size_t)vv * D + o, acc);
}

extern "C" void kernel_launch(void* const* d_in, const int* in_sizes, int n_in,
                              void* d_out, int out_size, void* d_ws, size_t ws_size,
                              hipStream_t stream) {
    const float* x    = (const float*)d_in[0];
    const float* W    = (const float*)d_in[1];
    const int*   u    = (const int*)d_in[2];
    const int*   v    = (const int*)d_in[3];
    const int*   widx = (const int*)d_in[4];
    float* out = (float*)d_out;

    int E = in_sizes[2];
    int n4 = out_size / 4;

    // Workspace layout (int2 first for 8B alignment).
    int2* sorted = (int2*)d_ws;                 // E int2
    int*  histT  = (int*)(sorted + E);          // NBINS*CHUNKS
    int*  bsum   = histT + NBINS * CHUNKS;      // scan block sums (<=64)
    int*  bstart = bsum + 64;                   // NBINS+1
    size_t needed = (size_t)E * 8 + ((size_t)NBINS * CHUNKS + 64 + NBINS + 1) * 4;

    hipMemsetAsync(d_out, 0, (size_t)out_size * sizeof(float), stream);

    if (ws_size < needed) {
        int total = E * 16;
        edge_scatter_kernel<<<(total + 255) / 256, 256, 0, stream>>>(x, W, u, v, widx, out, E);
        relu_kernel<<<(n4 + 255) / 256, 256, 0, stream>>>(out, n4);
        return;
    }

    int chunk = (E + CHUNKS - 1) / CHUNKS;
    int nscan = NBINS * CHUNKS;                 // 65536
    int NB = (nscan + 1023) / 1024;             // 64

    hist_widx_kernel<<<CHUNKS, 256, 0, stream>>>(widx, histT, E, chunk);
    scan1_kernel<<<NB, 256, 0, stream>>>(histT, bsum, nscan);
    scan2_kernel<<<1, 64, 0, stream>>>(bsum, NB);
    scan3_kernel<<<(nscan + 255) / 256, 256, 0, stream>>>(histT, bsum, bstart, nscan, E);
    scatter_widx_kernel<<<CHUNKS, 256, 0, stream>>>(u, v, widx, histT, sorted, E, chunk);

    mfma_compute_kernel<<<NBINS * BLOCKS_PER_BIN, 256, 0, stream>>>(x, W, bstart, sorted, out);
    relu_kernel<<<(n4 + 255) / 256, 256, 0, stream>>>(out, n4);
}

// Round 4
// 359.712 us; speedup vs baseline: 1.2172x; 1.2172x over previous
//
#include <hip/hip_runtime.h>

#define D 16
#define NBINS 256
// bf16 LDS stride per weight matrix: 256 elems + 8 pad = 264 shorts (528 B)
// -> bank offset rotates by 4 per matrix, spreading quad conflicts.
#define WSTRIDE 264

typedef __bf16 bf16x8 __attribute__((ext_vector_type(8)));

// ---------------- CSR build: counting sort of edges by v ----------------

__global__ __launch_bounds__(256) void hist_kernel(const int* __restrict__ v,
                                                   int* __restrict__ cnt, int E) {
    int e = blockIdx.x * 256 + threadIdx.x;
    if (e < E) atomicAdd(&cnt[v[e]], 1);
}

// Per-block exclusive scan over 1024 elements (in place), block totals to bsum.
__global__ __launch_bounds__(256) void scan1_kernel(int* __restrict__ a,
                                                    int* __restrict__ bsum, int n) {
    __shared__ int wsum[4];
    int t = threadIdx.x;
    int base = blockIdx.x * 1024 + t * 4;
    int c0 = (base + 0 < n) ? a[base + 0] : 0;
    int c1 = (base + 1 < n) ? a[base + 1] : 0;
    int c2 = (base + 2 < n) ? a[base + 2] : 0;
    int c3 = (base + 3 < n) ? a[base + 3] : 0;
    int tsum = c0 + c1 + c2 + c3;
    int lane = t & 63, wid = t >> 6;
    int incl = tsum;
    for (int d = 1; d < 64; d <<= 1) {
        int m = __shfl_up(incl, d, 64);
        if (lane >= d) incl += m;
    }
    if (lane == 63) wsum[wid] = incl;
    __syncthreads();
    if (t == 0) {
        int s = 0;
        for (int k = 0; k < 4; k++) { int tmp = wsum[k]; wsum[k] = s; s += tmp; }
        bsum[blockIdx.x] = s;
    }
    __syncthreads();
    int excl = incl - tsum + wsum[wid];
    if (base + 0 < n) a[base + 0] = excl;
    if (base + 1 < n) a[base + 1] = excl + c0;
    if (base + 2 < n) a[base + 2] = excl + c0 + c1;
    if (base + 3 < n) a[base + 3] = excl + c0 + c1 + c2;
}

// Parallel exclusive scan of <=128 block sums, one block of 128 threads.
__global__ __launch_bounds__(128) void scan2_kernel(int* __restrict__ bsum, int nb) {
    __shared__ int ws[2];
    int t = threadIdx.x;
    int val = (t < nb) ? bsum[t] : 0;
    int lane = t & 63, wv = t >> 6;
    int incl = val;
    for (int d = 1; d < 64; d <<= 1) {
        int m = __shfl_up(incl, d, 64);
        if (lane >= d) incl += m;
    }
    if (lane == 63) ws[wv] = incl;
    __syncthreads();
    int add = (wv == 1) ? ws[0] : 0;
    if (t < nb) bsum[t] = incl - val + add;
}

// Add back block offsets; duplicate into cursor array; sentinel off[n]=E.
__global__ __launch_bounds__(256) void scan3_kernel(int* __restrict__ off,
                                                    int* __restrict__ cur,
                                                    const int* __restrict__ bsum,
                                                    int n, int E) {
    int idx = blockIdx.x * 256 + threadIdx.x;
    if (idx < n) {
        int val = off[idx] + bsum[idx >> 10];
        off[idx] = val;
        cur[idx] = val;
    }
    if (idx == 0) off[n] = E;
}

// Scatter packed (u | widx<<17) payload into v-sorted order (4B/edge).
__global__ __launch_bounds__(256) void scatter_kernel(const int* __restrict__ u,
                                                      const int* __restrict__ v,
                                                      const int* __restrict__ widx,
                                                      int* __restrict__ cur,
                                                      int* __restrict__ spack, int E) {
    int e = blockIdx.x * 256 + threadIdx.x;
    if (e >= E) return;
    int pos = atomicAdd(&cur[v[e]], 1);
    spack[pos] = u[e] | (widx[e] << 17);
}

// ---------------- Gather: all 256 W in LDS (bf16), wave-per-node ----------

__global__ __launch_bounds__(1024) void gather_kernel(const float* __restrict__ x,
                                                      const float* __restrict__ W,
                                                      const int* __restrict__ off,
                                                      const int* __restrict__ spack,
                                                      float* __restrict__ out, int N) {
    __shared__ __attribute__((aligned(16))) short lw[NBINS * WSTRIDE];  // 132 KB
    int t = threadIdx.x;

    // Stage all of W into LDS as bf16. Row r = (w,o); layout: half h of row o
    // of matrix w at short index w*WSTRIDE + h*128 + o*8.
    for (int r = t; r < NBINS * 16; r += 1024) {
        int w = r >> 4, o = r & 15;
        const float4* src = (const float4*)(W + (size_t)r * 16);
        float4 a = src[0], b = src[1], c = src[2], d = src[3];
        bf16x8 p0, p1;
        p0[0] = (__bf16)a.x; p0[1] = (__bf16)a.y; p0[2] = (__bf16)a.z; p0[3] = (__bf16)a.w;
        p0[4] = (__bf16)b.x; p0[5] = (__bf16)b.y; p0[6] = (__bf16)b.z; p0[7] = (__bf16)b.w;
        p1[0] = (__bf16)c.x; p1[1] = (__bf16)c.y; p1[2] = (__bf16)c.z; p1[3] = (__bf16)c.w;
        p1[4] = (__bf16)d.x; p1[5] = (__bf16)d.y; p1[6] = (__bf16)d.z; p1[7] = (__bf16)d.w;
        short* dst = lw + w * WSTRIDE + o * 8;
        *(bf16x8*)dst = p0;
        *(bf16x8*)(dst + 128) = p1;
    }
    __syncthreads();

    int wave = t >> 6, lane = t & 63;
    int q = lane >> 4, o = lane & 15;

    for (int n = blockIdx.x * 16 + wave; n < N; n += gridDim.x * 16) {
        int s = off[n], e = off[n + 1];
        float acc = 0.0f;

        int jj = s + q;
        int m = (jj < e) ? spack[jj] : -1;  // prefetch first group's meta
        for (int j = s; j < e; j += 4) {
            int jn = j + 4 + q;
            int mn = (jn < e) ? spack[jn] : -1;  // prefetch next group's meta
            if (m >= 0) {
                int uu = m & 0x1FFFF;
                int ww = m >> 17;
                const float4* xp = (const float4*)(x + (size_t)uu * D);
                float4 x0 = xp[0], x1 = xp[1], x2 = xp[2], x3 = xp[3];
                const short* wrow = lw + ww * WSTRIDE + o * 8;
                bf16x8 wa = *(const bf16x8*)wrow;
                bf16x8 wb = *(const bf16x8*)(wrow + 128);
                acc += (float)wa[0] * x0.x + (float)wa[1] * x0.y +
                       (float)wa[2] * x0.z + (float)wa[3] * x0.w;
                acc += (float)wa[4] * x1.x + (float)wa[5] * x1.y +
                       (float)wa[6] * x1.z + (float)wa[7] * x1.w;
                acc += (float)wb[0] * x2.x + (float)wb[1] * x2.y +
                       (float)wb[2] * x2.z + (float)wb[3] * x2.w;
                acc += (float)wb[4] * x3.x + (float)wb[5] * x3.y +
                       (float)wb[6] * x3.z + (float)wb[7] * x3.w;
            }
            m = mn;
        }
        // Reduce across the 4 quads; every lane ends with the full sum.
        acc += __shfl_xor(acc, 16, 64);
        acc += __shfl_xor(acc, 32, 64);
        if (lane < 16) out[(size_t)n * D + lane] = fmaxf(acc, 0.0f);
    }
}

// ---------------- fallback (round-1 path) if workspace too small ----------

__global__ __launch_bounds__(256) void edge_scatter_kernel(
    const float* __restrict__ x, const float* __restrict__ W,
    const int* __restrict__ u, const int* __restrict__ v,
    const int* __restrict__ widx, float* __restrict__ out, int E) {
    int tid = blockIdx.x * 256 + threadIdx.x;
    int e = tid >> 4;
    int o = tid & 15;
    if (e >= E) return;
    int w = widx[e], uu = u[e], vv = v[e];
    const float* Wr = W + (size_t)w * (D * D) + o * D;
    float4 w0 = *(const float4*)(Wr + 0);
    float4 w1 = *(const float4*)(Wr + 4);
    float4 w2 = *(const float4*)(Wr + 8);
    float4 w3 = *(const float4*)(Wr + 12);
    float xv = x[uu * D + o];
    float acc = 0.0f;
    acc += w0.x * __shfl(xv, 0, 16);  acc += w0.y * __shfl(xv, 1, 16);
    acc += w0.z * __shfl(xv, 2, 16);  acc += w0.w * __shfl(xv, 3, 16);
    acc += w1.x * __shfl(xv, 4, 16);  acc += w1.y * __shfl(xv, 5, 16);
    acc += w1.z * __shfl(xv, 6, 16);  acc += w1.w * __shfl(xv, 7, 16);
    acc += w2.x * __shfl(xv, 8, 16);  acc += w2.y * __shfl(xv, 9, 16);
    acc += w2.z * __shfl(xv, 10, 16); acc += w2.w * __shfl(xv, 11, 16);
    acc += w3.x * __shfl(xv, 12, 16); acc += w3.y * __shfl(xv, 13, 16);
    acc += w3.z * __shfl(xv, 14, 16); acc += w3.w * __shfl(xv, 15, 16);
    atomicAdd(out + (size_t)vv * D + o, acc);
}

__global__ __launch_bounds__(256) void relu_kernel(float* __restrict__ out, int n4) {
    int i = blockIdx.x * 256 + threadIdx.x;
    if (i >= n4) return;
    float4* p = (float4*)out + i;
    float4 val = *p;
    val.x = fmaxf(val.x, 0.0f); val.y = fmaxf(val.y, 0.0f);
    val.z = fmaxf(val.z, 0.0f); val.w = fmaxf(val.w, 0.0f);
    *p = val;
}

extern "C" void kernel_launch(void* const* d_in, const int* in_sizes, int n_in,
                              void* d_out, int out_size, void* d_ws, size_t ws_size,
                              hipStream_t stream) {
    const float* x    = (const float*)d_in[0];
    const float* W    = (const float*)d_in[1];
    const int*   u    = (const int*)d_in[2];
    const int*   v    = (const int*)d_in[3];
    const int*   widx = (const int*)d_in[4];
    float* out = (float*)d_out;

    int E = in_sizes[2];
    int N = out_size / D;
    int n4 = out_size / 4;

    // Workspace layout
    int* off   = (int*)d_ws;       // N+1
    int* cur   = off + (N + 1);    // N
    int* bsum  = cur + N;          // 128
    int* spack = bsum + 128;       // E
    size_t needed = ((size_t)2 * N + 129 + (size_t)E) * sizeof(int);

    if (ws_size < needed) {
        hipMemsetAsync(d_out, 0, (size_t)out_size * sizeof(float), stream);
        int total = E * 16;
        edge_scatter_kernel<<<(total + 255) / 256, 256, 0, stream>>>(x, W, u, v, widx, out, E);
        relu_kernel<<<(n4 + 255) / 256, 256, 0, stream>>>(out, n4);
        return;
    }

    int NB = (N + 1023) / 1024;  // 98 for N=100000 (must be <=128 for scan2)

    hipMemsetAsync(off, 0, (size_t)(N + 1) * sizeof(int), stream);
    hist_kernel<<<(E + 255) / 256, 256, 0, stream>>>(v, off, E);
    scan1_kernel<<<NB, 256, 0, stream>>>(off, bsum, N);
    scan2_kernel<<<1, 128, 0, stream>>>(bsum, NB);
    scan3_kernel<<<(N + 255) / 256, 256, 0, stream>>>(off, cur, bsum, N, E);
    scatter_kernel<<<(E + 255) / 256, 256, 0, stream>>>(u, v, widx, cur, spack, E);

    gather_kernel<<<256, 1024, 0, stream>>>(x, W, off, spack, out, N);
}

// Round 5
// 328.718 us; speedup vs baseline: 1.3320x; 1.0943x over previous
//
#include <hip/hip_runtime.h>

#define D 16
#define BSHIFT 7            // 128 nodes per bucket
#define BNODES 128
#define NBUCKMAX 1024
#define CHUNK 8192          // edges per count/scatter block

typedef __bf16 bf16x8 __attribute__((ext_vector_type(8)));
typedef __bf16 bf16x4 __attribute__((ext_vector_type(4)));

// ---------------- W fp32 -> bf16 conversion (128 KB, L2-resident) --------

__global__ __launch_bounds__(256) void wconv_kernel(const float* __restrict__ W,
                                                    __bf16* __restrict__ wbf, int n) {
    int i = blockIdx.x * 256 + threadIdx.x;
    if (i * 4 + 3 < n) {
        float4 f = ((const float4*)W)[i];
        bf16x4 o = {(__bf16)f.x, (__bf16)f.y, (__bf16)f.z, (__bf16)f.w};
        ((bf16x4*)wbf)[i] = o;
    }
}

// ---------------- bucket counting (bin = v>>7) ----------------------------

__global__ __launch_bounds__(256) void count_kernel(const int* __restrict__ v,
                                                    int* __restrict__ cnt,
                                                    int E, int nbuck) {
    __shared__ int h[NBUCKMAX];
    int t = threadIdx.x;
    for (int i = t; i < NBUCKMAX; i += 256) h[i] = 0;
    __syncthreads();
    int base = blockIdx.x * CHUNK;
    int end = min(E, base + CHUNK);
    for (int j = base + t; j < end; j += 256) atomicAdd(&h[v[j] >> BSHIFT], 1);
    __syncthreads();
    for (int i = t; i < nbuck; i += 256)
        if (h[i]) atomicAdd(&cnt[i], h[i]);
}

// ---------------- exclusive scan of <=1024 bucket counts (1 block) --------

__global__ __launch_bounds__(256) void scan_kernel(const int* __restrict__ cnt,
                                                   int* __restrict__ bstart,
                                                   int* __restrict__ cursor,
                                                   int nbuck, int E) {
    __shared__ int wsum[4];
    int t = threadIdx.x;
    int i0 = t * 4;
    int c0 = (i0 + 0 < nbuck) ? cnt[i0 + 0] : 0;
    int c1 = (i0 + 1 < nbuck) ? cnt[i0 + 1] : 0;
    int c2 = (i0 + 2 < nbuck) ? cnt[i0 + 2] : 0;
    int c3 = (i0 + 3 < nbuck) ? cnt[i0 + 3] : 0;
    int tsum = c0 + c1 + c2 + c3;
    int lane = t & 63, wid = t >> 6;
    int incl = tsum;
    for (int d = 1; d < 64; d <<= 1) {
        int m = __shfl_up(incl, d, 64);
        if (lane >= d) incl += m;
    }
    if (lane == 63) wsum[wid] = incl;
    __syncthreads();
    if (t == 0) {
        int s = 0;
        for (int k = 0; k < 4; k++) { int tmp = wsum[k]; wsum[k] = s; s += tmp; }
    }
    __syncthreads();
    int excl = incl - tsum + wsum[wid];
    int p0 = excl, p1 = excl + c0, p2 = excl + c0 + c1, p3 = excl + c0 + c1 + c2;
    if (i0 + 0 < nbuck) { bstart[i0 + 0] = p0; cursor[i0 + 0] = p0; }
    if (i0 + 1 < nbuck) { bstart[i0 + 1] = p1; cursor[i0 + 1] = p1; }
    if (i0 + 2 < nbuck) { bstart[i0 + 2] = p2; cursor[i0 + 2] = p2; }
    if (i0 + 3 < nbuck) { bstart[i0 + 3] = p3; cursor[i0 + 3] = p3; }
    if (t == 0) bstart[nbuck] = E;
}

// ---------------- bin-scatter: packed 4B payload u|vlo<<17|widx<<24 -------

__global__ __launch_bounds__(256) void scatter_bin_kernel(const int* __restrict__ u,
                                                          const int* __restrict__ v,
                                                          const int* __restrict__ widx,
                                                          int* __restrict__ cursor,
                                                          int* __restrict__ spack,
                                                          int E, int nbuck) {
    __shared__ int h[NBUCKMAX];
    __shared__ int lc[NBUCKMAX];
    int t = threadIdx.x;
    for (int i = t; i < NBUCKMAX; i += 256) h[i] = 0;
    __syncthreads();
    int base = blockIdx.x * CHUNK;
    int end = min(E, base + CHUNK);
    for (int j = base + t; j < end; j += 256) atomicAdd(&h[v[j] >> BSHIFT], 1);
    __syncthreads();
    for (int i = t; i < nbuck; i += 256) {
        int c = h[i];
        h[i] = c ? atomicAdd(&cursor[i], c) : 0;
        lc[i] = 0;
    }
    __syncthreads();
    for (int j = base + t; j < end; j += 256) {
        int vv = v[j];
        int bin = vv >> BSHIFT;
        int pos = h[bin] + atomicAdd(&lc[bin], 1);
        spack[pos] = u[j] | ((vv & (BNODES - 1)) << 17) | (widx[j] << 24);
    }
}

// ---------------- per-bucket compute: LDS accumulator, no global atomics --

__global__ __launch_bounds__(256) void bucket_compute_kernel(const float* __restrict__ x,
                                                             const __bf16* __restrict__ wbf,
                                                             const int* __restrict__ bstart,
                                                             const int* __restrict__ spack,
                                                             float* __restrict__ out, int N) {
    __shared__ float acc[BNODES * D];  // 8 KB
    int t = threadIdx.x;
    float4* acc4 = (float4*)acc;
    for (int i = t; i < BNODES * D / 4; i += 256)
        acc4[i] = make_float4(0.f, 0.f, 0.f, 0.f);
    __syncthreads();

    int b = blockIdx.x;
    int s = bstart[b], e = bstart[b + 1];
    int g = t >> 4;      // 16 edge-groups per block
    int o = t & 15;      // output component per lane

    int j = s + g;
    unsigned p = (j < e) ? (unsigned)spack[j] : 0u;
    for (; j < e; j += 16) {
        int jn = j + 16;
        unsigned pn = (jn < e) ? (unsigned)spack[jn] : 0u;  // prefetch next payload

        unsigned uu  = p & 0x1FFFFu;
        unsigned vlo = (p >> 17) & (BNODES - 1);
        unsigned ww  = p >> 24;

        const float4* xp = (const float4*)(x + (size_t)uu * D);
        float4 x0 = xp[0], x1 = xp[1], x2 = xp[2], x3 = xp[3];

        const bf16x8* wr = (const bf16x8*)(wbf + ((ww << 8) + (o << 4)));
        bf16x8 wa = wr[0], wb = wr[1];

        float d;
        d  = (float)wa[0] * x0.x + (float)wa[1] * x0.y +
             (float)wa[2] * x0.z + (float)wa[3] * x0.w;
        d += (float)wa[4] * x1.x + (float)wa[5] * x1.y +
             (float)wa[6] * x1.z + (float)wa[7] * x1.w;
        d += (float)wb[0] * x2.x + (float)wb[1] * x2.y +
             (float)wb[2] * x2.z + (float)wb[3] * x2.w;
        d += (float)wb[4] * x3.x + (float)wb[5] * x3.y +
             (float)wb[6] * x3.z + (float)wb[7] * x3.w;

        atomicAdd(&acc[(vlo << 4) + o], d);
        p = pn;
    }
    __syncthreads();

    int nodebase = b << BSHIFT;
    for (int i = t; i < BNODES * D / 4; i += 256) {
        int node = nodebase + (i >> 2);
        if (node < N) {
            float4 a = acc4[i];
            a.x = fmaxf(a.x, 0.f); a.y = fmaxf(a.y, 0.f);
            a.z = fmaxf(a.z, 0.f); a.w = fmaxf(a.w, 0.f);
            ((float4*)out)[(size_t)nodebase * 4 + i] = a;
        }
    }
}

// ---------------- fallback (round-1 path) ---------------------------------

__global__ __launch_bounds__(256) void edge_scatter_kernel(
    const float* __restrict__ x, const float* __restrict__ W,
    const int* __restrict__ u, const int* __restrict__ v,
    const int* __restrict__ widx, float* __restrict__ out, int E) {
    int tid = blockIdx.x * 256 + threadIdx.x;
    int e = tid >> 4;
    int o = tid & 15;
    if (e >= E) return;
    int w = widx[e], uu = u[e], vv = v[e];
    const float* Wr = W + (size_t)w * (D * D) + o * D;
    float4 w0 = *(const float4*)(Wr + 0);
    float4 w1 = *(const float4*)(Wr + 4);
    float4 w2 = *(const float4*)(Wr + 8);
    float4 w3 = *(const float4*)(Wr + 12);
    float xv = x[uu * D + o];
    float acc = 0.0f;
    acc += w0.x * __shfl(xv, 0, 16);  acc += w0.y * __shfl(xv, 1, 16);
    acc += w0.z * __shfl(xv, 2, 16);  acc += w0.w * __shfl(xv, 3, 16);
    acc += w1.x * __shfl(xv, 4, 16);  acc += w1.y * __shfl(xv, 5, 16);
    acc += w1.z * __shfl(xv, 6, 16);  acc += w1.w * __shfl(xv, 7, 16);
    acc += w2.x * __shfl(xv, 8, 16);  acc += w2.y * __shfl(xv, 9, 16);
    acc += w2.z * __shfl(xv, 10, 16); acc += w2.w * __shfl(xv, 11, 16);
    acc += w3.x * __shfl(xv, 12, 16); acc += w3.y * __shfl(xv, 13, 16);
    acc += w3.z * __shfl(xv, 14, 16); acc += w3.w * __shfl(xv, 15, 16);
    atomicAdd(out + (size_t)vv * D + o, acc);
}

__global__ __launch_bounds__(256) void relu_kernel(float* __restrict__ out, int n4) {
    int i = blockIdx.x * 256 + threadIdx.x;
    if (i >= n4) return;
    float4* p = (float4*)out + i;
    float4 val = *p;
    val.x = fmaxf(val.x, 0.0f); val.y = fmaxf(val.y, 0.0f);
    val.z = fmaxf(val.z, 0.0f); val.w = fmaxf(val.w, 0.0f);
    *p = val;
}

extern "C" void kernel_launch(void* const* d_in, const int* in_sizes, int n_in,
                              void* d_out, int out_size, void* d_ws, size_t ws_size,
                              hipStream_t stream) {
    const float* x    = (const float*)d_in[0];
    const float* W    = (const float*)d_in[1];
    const int*   u    = (const int*)d_in[2];
    const int*   v    = (const int*)d_in[3];
    const int*   widx = (const int*)d_in[4];
    float* out = (float*)d_out;

    int E = in_sizes[2];
    int Wn = in_sizes[1];          // 256*16*16 = 65536
    int N = out_size / D;
    int n4 = out_size / 4;
    int nbuck = (N + BNODES - 1) >> BSHIFT;

    // Workspace layout (16B-aligned segments).
    size_t off0 = 0;                                        // spack: E ints
    size_t off1 = (off0 + (size_t)E * 4 + 15) & ~15ull;     // wbf: Wn bf16
    size_t off2 = (off1 + (size_t)Wn * 2 + 15) & ~15ull;    // cnt: NBUCKMAX
    size_t off3 = off2 + NBUCKMAX * 4;                      // cursor: NBUCKMAX
    size_t off4 = off3 + NBUCKMAX * 4;                      // bstart: NBUCKMAX+1
    size_t needed = off4 + (NBUCKMAX + 1) * 4;

    bool ok = (ws_size >= needed) && (N <= (1 << 17)) && (nbuck <= NBUCKMAX) &&
              (Wn <= 256 * D * D) && ((Wn & 3) == 0);

    if (!ok) {
        hipMemsetAsync(d_out, 0, (size_t)out_size * sizeof(float), stream);
        int total = E * 16;
        edge_scatter_kernel<<<(total + 255) / 256, 256, 0, stream>>>(x, W, u, v, widx, out, E);
        relu_kernel<<<(n4 + 255) / 256, 256, 0, stream>>>(out, n4);
        return;
    }

    int*    spack  = (int*)((char*)d_ws + off0);
    __bf16* wbf    = (__bf16*)((char*)d_ws + off1);
    int*    cnt    = (int*)((char*)d_ws + off2);
    int*    cursor = (int*)((char*)d_ws + off3);
    int*    bstart = (int*)((char*)d_ws + off4);

    int nchunk = (E + CHUNK - 1) / CHUNK;

    hipMemsetAsync(cnt, 0, NBUCKMAX * sizeof(int), stream);
    wconv_kernel<<<(Wn / 4 + 255) / 256, 256, 0, stream>>>(W, wbf, Wn);
    count_kernel<<<nchunk, 256, 0, stream>>>(v, cnt, E, nbuck);
    scan_kernel<<<1, 256, 0, stream>>>(cnt, bstart, cursor, nbuck, E);
    scatter_bin_kernel<<<nchunk, 256, 0, stream>>>(u, v, widx, cursor, spack, E, nbuck);
    bucket_compute_kernel<<<nbuck, 256, 0, stream>>>(x, wbf, bstart, spack, out, N);
}

// Round 6
// 291.155 us; speedup vs baseline: 1.5038x; 1.1290x over previous
//
#include <hip/hip_runtime.h>

#define D 16
#define BSHIFT 7            // 128 nodes per bucket
#define BNODES 128
#define NBUCKMAX 1024
#define CHUNK 8192          // edges per count/scatter block
#define CB 512              // compute block threads (32 edge-groups)

typedef __bf16 bf16x8 __attribute__((ext_vector_type(8)));
typedef __bf16 bf16x4 __attribute__((ext_vector_type(4)));

// ---------------- W fp32 -> bf16 conversion (128 KB, L2-resident) --------

__global__ __launch_bounds__(256) void wconv_kernel(const float* __restrict__ W,
                                                    __bf16* __restrict__ wbf, int n) {
    int i = blockIdx.x * 256 + threadIdx.x;
    if (i * 4 + 3 < n) {
        float4 f = ((const float4*)W)[i];
        bf16x4 o = {(__bf16)f.x, (__bf16)f.y, (__bf16)f.z, (__bf16)f.w};
        ((bf16x4*)wbf)[i] = o;
    }
}

// ---------------- bucket counting (bin = v>>7) ----------------------------

__global__ __launch_bounds__(256) void count_kernel(const int* __restrict__ v,
                                                    int* __restrict__ cnt,
                                                    int E, int nbuck) {
    __shared__ int h[NBUCKMAX];
    int t = threadIdx.x;
    for (int i = t; i < NBUCKMAX; i += 256) h[i] = 0;
    __syncthreads();
    int base = blockIdx.x * CHUNK;
    int end = min(E, base + CHUNK);
    for (int j = base + t; j < end; j += 256) atomicAdd(&h[v[j] >> BSHIFT], 1);
    __syncthreads();
    for (int i = t; i < nbuck; i += 256)
        if (h[i]) atomicAdd(&cnt[i], h[i]);
}

// ---------------- exclusive scan of <=1024 bucket counts (1 block) --------

__global__ __launch_bounds__(256) void scan_kernel(const int* __restrict__ cnt,
                                                   int* __restrict__ bstart,
                                                   int* __restrict__ cursor,
                                                   int nbuck, int E) {
    __shared__ int wsum[4];
    int t = threadIdx.x;
    int i0 = t * 4;
    int c0 = (i0 + 0 < nbuck) ? cnt[i0 + 0] : 0;
    int c1 = (i0 + 1 < nbuck) ? cnt[i0 + 1] : 0;
    int c2 = (i0 + 2 < nbuck) ? cnt[i0 + 2] : 0;
    int c3 = (i0 + 3 < nbuck) ? cnt[i0 + 3] : 0;
    int tsum = c0 + c1 + c2 + c3;
    int lane = t & 63, wid = t >> 6;
    int incl = tsum;
    for (int d = 1; d < 64; d <<= 1) {
        int m = __shfl_up(incl, d, 64);
        if (lane >= d) incl += m;
    }
    if (lane == 63) wsum[wid] = incl;
    __syncthreads();
    if (t == 0) {
        int s = 0;
        for (int k = 0; k < 4; k++) { int tmp = wsum[k]; wsum[k] = s; s += tmp; }
    }
    __syncthreads();
    int excl = incl - tsum + wsum[wid];
    int p0 = excl, p1 = excl + c0, p2 = excl + c0 + c1, p3 = excl + c0 + c1 + c2;
    if (i0 + 0 < nbuck) { bstart[i0 + 0] = p0; cursor[i0 + 0] = p0; }
    if (i0 + 1 < nbuck) { bstart[i0 + 1] = p1; cursor[i0 + 1] = p1; }
    if (i0 + 2 < nbuck) { bstart[i0 + 2] = p2; cursor[i0 + 2] = p2; }
    if (i0 + 3 < nbuck) { bstart[i0 + 3] = p3; cursor[i0 + 3] = p3; }
    if (t == 0) bstart[nbuck] = E;
}

// ---------------- bin-scatter: packed 4B payload u|vlo<<17|widx<<24 -------

__global__ __launch_bounds__(256) void scatter_bin_kernel(const int* __restrict__ u,
                                                          const int* __restrict__ v,
                                                          const int* __restrict__ widx,
                                                          int* __restrict__ cursor,
                                                          int* __restrict__ spack,
                                                          int E, int nbuck) {
    __shared__ int h[NBUCKMAX];
    __shared__ int lc[NBUCKMAX];
    int t = threadIdx.x;
    for (int i = t; i < NBUCKMAX; i += 256) h[i] = 0;
    __syncthreads();
    int base = blockIdx.x * CHUNK;
    int end = min(E, base + CHUNK);
    for (int j = base + t; j < end; j += 256) atomicAdd(&h[v[j] >> BSHIFT], 1);
    __syncthreads();
    for (int i = t; i < nbuck; i += 256) {
        int c = h[i];
        h[i] = c ? atomicAdd(&cursor[i], c) : 0;
        lc[i] = 0;
    }
    __syncthreads();
    for (int j = base + t; j < end; j += 256) {
        int vv = v[j];
        int bin = vv >> BSHIFT;
        int pos = h[bin] + atomicAdd(&lc[bin], 1);
        spack[pos] = u[j] | ((vv & (BNODES - 1)) << 17) | (widx[j] << 24);
    }
}

// ---- per-bucket compute: LDS accumulator, 4-edge ILP, no global atomics --

__global__ __launch_bounds__(CB) void bucket_compute_kernel(const float* __restrict__ x,
                                                            const __bf16* __restrict__ wbf,
                                                            const int* __restrict__ bstart,
                                                            const int* __restrict__ spack,
                                                            float* __restrict__ out, int N) {
    __shared__ float acc[BNODES * D];  // 8 KB
    int t = threadIdx.x;
    float4* acc4 = (float4*)acc;
    for (int i = t; i < BNODES * D / 4; i += CB)
        acc4[i] = make_float4(0.f, 0.f, 0.f, 0.f);
    __syncthreads();

    int b = blockIdx.x;
    int s = bstart[b], e = bstart[b + 1];
    int cnt = e - s;
    int g = t >> 4;      // 32 edge-groups per block
    int o = t & 15;      // output component per lane

    // Contiguous per-group range -> 4 independent edges in flight per iter.
    int per = (cnt + 31) >> 5;
    int gs = s + g * per;
    int ge = min(e, gs + per);

    for (int j = gs; j < ge; j += 4) {
        int last = ge - 1;
        int i0 = j;
        int i1 = min(j + 1, last);
        int i2 = min(j + 2, last);
        int i3 = min(j + 3, last);
        bool v1 = j + 1 < ge, v2 = j + 2 < ge, v3 = j + 3 < ge;

        unsigned p0 = (unsigned)spack[i0];
        unsigned p1 = (unsigned)spack[i1];
        unsigned p2 = (unsigned)spack[i2];
        unsigned p3 = (unsigned)spack[i3];

        const float4* xp0 = (const float4*)(x + (size_t)(p0 & 0x1FFFFu) * D);
        const float4* xp1 = (const float4*)(x + (size_t)(p1 & 0x1FFFFu) * D);
        const float4* xp2 = (const float4*)(x + (size_t)(p2 & 0x1FFFFu) * D);
        const float4* xp3 = (const float4*)(x + (size_t)(p3 & 0x1FFFFu) * D);
        const bf16x8* wr0 = (const bf16x8*)(wbf + (((p0 >> 24) << 8) + (o << 4)));
        const bf16x8* wr1 = (const bf16x8*)(wbf + (((p1 >> 24) << 8) + (o << 4)));
        const bf16x8* wr2 = (const bf16x8*)(wbf + (((p2 >> 24) << 8) + (o << 4)));
        const bf16x8* wr3 = (const bf16x8*)(wbf + (((p3 >> 24) << 8) + (o << 4)));

        // Issue all loads; consume after (compiler schedules waits late).
        float4 a0 = xp0[0], a1 = xp0[1], a2 = xp0[2], a3 = xp0[3];
        float4 b0 = xp1[0], b1 = xp1[1], b2 = xp1[2], b3 = xp1[3];
        float4 c0 = xp2[0], c1 = xp2[1], c2 = xp2[2], c3 = xp2[3];
        float4 d0 = xp3[0], d1 = xp3[1], d2 = xp3[2], d3 = xp3[3];
        bf16x8 wa0 = wr0[0], wb0 = wr0[1];
        bf16x8 wa1 = wr1[0], wb1 = wr1[1];
        bf16x8 wa2 = wr2[0], wb2 = wr2[1];
        bf16x8 wa3 = wr3[0], wb3 = wr3[1];

        float s0, s1, s2, s3;
        s0  = (float)wa0[0]*a0.x + (float)wa0[1]*a0.y + (float)wa0[2]*a0.z + (float)wa0[3]*a0.w;
        s0 += (float)wa0[4]*a1.x + (float)wa0[5]*a1.y + (float)wa0[6]*a1.z + (float)wa0[7]*a1.w;
        s0 += (float)wb0[0]*a2.x + (float)wb0[1]*a2.y + (float)wb0[2]*a2.z + (float)wb0[3]*a2.w;
        s0 += (float)wb0[4]*a3.x + (float)wb0[5]*a3.y + (float)wb0[6]*a3.z + (float)wb0[7]*a3.w;

        s1  = (float)wa1[0]*b0.x + (float)wa1[1]*b0.y + (float)wa1[2]*b0.z + (float)wa1[3]*b0.w;
        s1 += (float)wa1[4]*b1.x + (float)wa1[5]*b1.y + (float)wa1[6]*b1.z + (float)wa1[7]*b1.w;
        s1 += (float)wb1[0]*b2.x + (float)wb1[1]*b2.y + (float)wb1[2]*b2.z + (float)wb1[3]*b2.w;
        s1 += (float)wb1[4]*b3.x + (float)wb1[5]*b3.y + (float)wb1[6]*b3.z + (float)wb1[7]*b3.w;

        s2  = (float)wa2[0]*c0.x + (float)wa2[1]*c0.y + (float)wa2[2]*c0.z + (float)wa2[3]*c0.w;
        s2 += (float)wa2[4]*c1.x + (float)wa2[5]*c1.y + (float)wa2[6]*c1.z + (float)wa2[7]*c1.w;
        s2 += (float)wb2[0]*c2.x + (float)wb2[1]*c2.y + (float)wb2[2]*c2.z + (float)wb2[3]*c2.w;
        s2 += (float)wb2[4]*c3.x + (float)wb2[5]*c3.y + (float)wb2[6]*c3.z + (float)wb2[7]*c3.w;

        s3  = (float)wa3[0]*d0.x + (float)wa3[1]*d0.y + (float)wa3[2]*d0.z + (float)wa3[3]*d0.w;
        s3 += (float)wa3[4]*d1.x + (float)wa3[5]*d1.y + (float)wa3[6]*d1.z + (float)wa3[7]*d1.w;
        s3 += (float)wb3[0]*d2.x + (float)wb3[1]*d2.y + (float)wb3[2]*d2.z + (float)wb3[3]*d2.w;
        s3 += (float)wb3[4]*d3.x + (float)wb3[5]*d3.y + (float)wb3[6]*d3.z + (float)wb3[7]*d3.w;

        atomicAdd(&acc[(((p0 >> 17) & 127u) << 4) + o], s0);
        if (v1) atomicAdd(&acc[(((p1 >> 17) & 127u) << 4) + o], s1);
        if (v2) atomicAdd(&acc[(((p2 >> 17) & 127u) << 4) + o], s2);
        if (v3) atomicAdd(&acc[(((p3 >> 17) & 127u) << 4) + o], s3);
    }
    __syncthreads();

    int nodebase = b << BSHIFT;
    for (int i = t; i < BNODES * D / 4; i += CB) {
        int node = nodebase + (i >> 2);
        if (node < N) {
            float4 a = acc4[i];
            a.x = fmaxf(a.x, 0.f); a.y = fmaxf(a.y, 0.f);
            a.z = fmaxf(a.z, 0.f); a.w = fmaxf(a.w, 0.f);
            ((float4*)out)[(size_t)nodebase * 4 + i] = a;
        }
    }
}

// ---------------- fallback (round-1 path) ---------------------------------

__global__ __launch_bounds__(256) void edge_scatter_kernel(
    const float* __restrict__ x, const float* __restrict__ W,
    const int* __restrict__ u, const int* __restrict__ v,
    const int* __restrict__ widx, float* __restrict__ out, int E) {
    int tid = blockIdx.x * 256 + threadIdx.x;
    int e = tid >> 4;
    int o = tid & 15;
    if (e >= E) return;
    int w = widx[e], uu = u[e], vv = v[e];
    const float* Wr = W + (size_t)w * (D * D) + o * D;
    float4 w0 = *(const float4*)(Wr + 0);
    float4 w1 = *(const float4*)(Wr + 4);
    float4 w2 = *(const float4*)(Wr + 8);
    float4 w3 = *(const float4*)(Wr + 12);
    float xv = x[uu * D + o];
    float acc = 0.0f;
    acc += w0.x * __shfl(xv, 0, 16);  acc += w0.y * __shfl(xv, 1, 16);
    acc += w0.z * __shfl(xv, 2, 16);  acc += w0.w * __shfl(xv, 3, 16);
    acc += w1.x * __shfl(xv, 4, 16);  acc += w1.y * __shfl(xv, 5, 16);
    acc += w1.z * __shfl(xv, 6, 16);  acc += w1.w * __shfl(xv, 7, 16);
    acc += w2.x * __shfl(xv, 8, 16);  acc += w2.y * __shfl(xv, 9, 16);
    acc += w2.z * __shfl(xv, 10, 16); acc += w2.w * __shfl(xv, 11, 16);
    acc += w3.x * __shfl(xv, 12, 16); acc += w3.y * __shfl(xv, 13, 16);
    acc += w3.z * __shfl(xv, 14, 16); acc += w3.w * __shfl(xv, 15, 16);
    atomicAdd(out + (size_t)vv * D + o, acc);
}

__global__ __launch_bounds__(256) void relu_kernel(float* __restrict__ out, int n4) {
    int i = blockIdx.x * 256 + threadIdx.x;
    if (i >= n4) return;
    float4* p = (float4*)out + i;
    float4 val = *p;
    val.x = fmaxf(val.x, 0.0f); val.y = fmaxf(val.y, 0.0f);
    val.z = fmaxf(val.z, 0.0f); val.w = fmaxf(val.w, 0.0f);
    *p = val;
}

extern "C" void kernel_launch(void* const* d_in, const int* in_sizes, int n_in,
                              void* d_out, int out_size, void* d_ws, size_t ws_size,
                              hipStream_t stream) {
    const float* x    = (const float*)d_in[0];
    const float* W    = (const float*)d_in[1];
    const int*   u    = (const int*)d_in[2];
    const int*   v    = (const int*)d_in[3];
    const int*   widx = (const int*)d_in[4];
    float* out = (float*)d_out;

    int E = in_sizes[2];
    int Wn = in_sizes[1];          // 256*16*16 = 65536
    int N = out_size / D;
    int n4 = out_size / 4;
    int nbuck = (N + BNODES - 1) >> BSHIFT;

    // Workspace layout (16B-aligned segments).
    size_t off0 = 0;                                        // spack: E ints
    size_t off1 = (off0 + (size_t)E * 4 + 15) & ~15ull;     // wbf: Wn bf16
    size_t off2 = (off1 + (size_t)Wn * 2 + 15) & ~15ull;    // cnt: NBUCKMAX
    size_t off3 = off2 + NBUCKMAX * 4;                      // cursor: NBUCKMAX
    size_t off4 = off3 + NBUCKMAX * 4;                      // bstart: NBUCKMAX+1
    size_t needed = off4 + (NBUCKMAX + 1) * 4;

    bool ok = (ws_size >= needed) && (N <= (1 << 17)) && (nbuck <= NBUCKMAX) &&
              (Wn <= 256 * D * D) && ((Wn & 3) == 0);

    if (!ok) {
        hipMemsetAsync(d_out, 0, (size_t)out_size * sizeof(float), stream);
        int total = E * 16;
        edge_scatter_kernel<<<(total + 255) / 256, 256, 0, stream>>>(x, W, u, v, widx, out, E);
        relu_kernel<<<(n4 + 255) / 256, 256, 0, stream>>>(out, n4);
        return;
    }

    int*    spack  = (int*)((char*)d_ws + off0);
    __bf16* wbf    = (__bf16*)((char*)d_ws + off1);
    int*    cnt    = (int*)((char*)d_ws + off2);
    int*    cursor = (int*)((char*)d_ws + off3);
    int*    bstart = (int*)((char*)d_ws + off4);

    int nchunk = (E + CHUNK - 1) / CHUNK;

    hipMemsetAsync(cnt, 0, NBUCKMAX * sizeof(int), stream);
    wconv_kernel<<<(Wn / 4 + 255) / 256, 256, 0, stream>>>(W, wbf, Wn);
    count_kernel<<<nchunk, 256, 0, stream>>>(v, cnt, E, nbuck);
    scan_kernel<<<1, 256, 0, stream>>>(cnt, bstart, cursor, nbuck, E);
    scatter_bin_kernel<<<nchunk, 256, 0, stream>>>(u, v, widx, cursor, spack, E, nbuck);
    bucket_compute_kernel<<<nbuck, CB, 0, stream>>>(x, wbf, bstart, spack, out, N);
}